// Round 5
// baseline (6898.019 us; speedup 1.0000x reference)
//
#include <hip/hip_runtime.h>
#include <hip/hip_bf16.h>

#define EPS 1e-5f

// ---------------------------------------------------------------------------
// Layouts:
//   external x : (N=128, C=2, T=256, V=18) row-major (t,v innermost)
//   internal   : (n, c, v, t)  -- t innermost
// Pipeline per block b: ugemm (1x1 channel GEMM) -> k_amixg (in-place A-mix +
// BN1 + ReLU over the 18 joints) -> k_tcn (residual 1x1 + 9-tap temporal conv,
// BN2 prefolded) -> k_smooth (EMA).
// N processed in chunks of NC chosen at runtime from ws_size.
// Per-chunk buffers: Us NC*589824, B1/B2 NC*294912 each, XB NC*9216.
// total bytes = 3,427,328 + NC*4,755,456  (NC=32 -> 155.6 MB)
// ---------------------------------------------------------------------------

__global__ __launch_bounds__(256, 4) void k_transpose(
    const float* __restrict__ in, float* __restrict__ out, int rows, int cols) {
  int i = blockIdx.x * 256 + threadIdx.x;
  if (i < rows * cols) {
    int r = i / cols, c = i % cols;
    out[c * rows + r] = in[i];
  }
}

// twT[(c*9+k)*Co + o] = tw[(o*Co+c)*9+k] * s2[o]   (bn2 scale prefolded)
__global__ __launch_bounds__(256, 4) void k_prep_tw(
    const float* __restrict__ tw, const float* __restrict__ bn2g,
    float* __restrict__ twT, int Co) {
  int i = blockIdx.x * 256 + threadIdx.x;
  int total = Co * Co * 9;
  if (i < total) {
    int o = i / (Co * 9);
    int r = i % (Co * 9);
    int c = r / 9, k = r % 9;
    float s2 = bn2g[o] * (1.0f / sqrtf(1.0f + EPS));
    twT[(c * 9 + k) * Co + o] = tw[i] * s2;
  }
}

// beta[o] = s2*tb + b2 + rb
__global__ __launch_bounds__(256, 4) void k_beta(
    const float* __restrict__ bn2g, const float* __restrict__ bn2b,
    const float* __restrict__ tb, const float* __restrict__ rb,
    float* __restrict__ beta, int Co) {
  int o = blockIdx.x * 256 + threadIdx.x;
  if (o < Co)
    beta[o] = bn2g[o] * (1.0f / sqrtf(1.0f + EPS)) * tb[o] + bn2b[o] + rb[o];
}

// block1 front (per n-chunk): data_bn + 1x1 (Ci=2) -> U1 (nc,64,18,256); also xb1
__global__ __launch_bounds__(256, 4) void k_front1(
    const float* __restrict__ x, const float* __restrict__ dbng,
    const float* __restrict__ dbnb, const float* __restrict__ gw,
    float* __restrict__ U1, float* __restrict__ xb1) {
  int n = blockIdx.x, t0 = blockIdx.y * 64;
  __shared__ float xb[2 * 64 * 18];  // [c][tt][v]
  const float rs = 1.0f / sqrtf(1.0f + EPS);
  for (int e = threadIdx.x; e < 2304; e += 256) {
    int c = e / 1152, r = e % 1152;  // r = tt*18+v
    int v = r % 18;
    xb[e] = x[(n * 2 + c) * 4608 + t0 * 18 + r] * (dbng[c * 18 + v] * rs) + dbnb[c * 18 + v];
  }
  __syncthreads();
  for (int e = threadIdx.x; e < 2304; e += 256) {
    int c = e / 1152, r = e % 1152;
    int v = r / 64, tt = r % 64;
    xb1[((size_t)(n * 2 + c) * 18 + v) * 256 + t0 + tt] = xb[c * 1152 + tt * 18 + v];
  }
  for (int e = threadIdx.x; e < 64 * 1152; e += 256) {
    int o = e / 1152, r = e % 1152;
    int v = r / 64, tt = r % 64;
    float g0 = gw[o * 2 + 0], g1 = gw[o * 2 + 1];
    U1[((size_t)(n * 64 + o) * 18 + v) * 256 + t0 + tt] =
        fmaf(g0, xb[tt * 18 + v], g1 * xb[1152 + tt * 18 + v]);
  }
}

// U = gwT^T * X over channels.  X:(nc,CI,18,T)  U:(nc,CO,18,T)  NP = 18*T
template <int CI, int CO>
__global__ __launch_bounds__(256, 4) void k_ugemm(
    const float* __restrict__ X, const float* __restrict__ gwT,
    float* __restrict__ Uo, int NP) {
  const int n = blockIdx.x;
  const int p0 = blockIdx.y * 128;
  const int o0 = blockIdx.z * 64;
  const int og = threadIdx.x & 15, pg = threadIdx.x >> 4;
  const int o = o0 + og * 4, p = p0 + pg * 8;
  __shared__ __align__(16) float xs[32 * 128];
  __shared__ __align__(16) float wsm[32 * 64];
  float acc[4][8] = {};
  const float* Xn = X + (size_t)n * CI * NP;
  for (int c0 = 0; c0 < CI; c0 += 32) {
    __syncthreads();
    for (int e = threadIdx.x; e < 1024; e += 256) {
      int c = e >> 5, j = (e & 31) << 2;
      *(float4*)&xs[c * 128 + j] = *(const float4*)&Xn[(size_t)(c0 + c) * NP + p0 + j];
    }
    for (int e = threadIdx.x; e < 512; e += 256) {
      int c = e >> 4, j = (e & 15) << 2;
      *(float4*)&wsm[c * 64 + j] = *(const float4*)&gwT[(size_t)(c0 + c) * CO + o0 + j];
    }
    __syncthreads();
#pragma unroll 8
    for (int c = 0; c < 32; c++) {
      float4 w4 = *(const float4*)&wsm[c * 64 + og * 4];
      float4 xa = *(const float4*)&xs[c * 128 + pg * 8];
      float4 xb2 = *(const float4*)&xs[c * 128 + pg * 8 + 4];
      float wr[4] = {w4.x, w4.y, w4.z, w4.w};
      float xr[8] = {xa.x, xa.y, xa.z, xa.w, xb2.x, xb2.y, xb2.z, xb2.w};
#pragma unroll
      for (int j = 0; j < 4; j++)
#pragma unroll
        for (int q = 0; q < 8; q++) acc[j][q] = fmaf(wr[j], xr[q], acc[j][q]);
    }
  }
  float* Un = Uo + (size_t)n * CO * NP;
#pragma unroll
  for (int j = 0; j < 4; j++) {
    *(float4*)&Un[(size_t)(o + j) * NP + p] =
        make_float4(acc[j][0], acc[j][1], acc[j][2], acc[j][3]);
    *(float4*)&Un[(size_t)(o + j) * NP + p + 4] =
        make_float4(acc[j][4], acc[j][5], acc[j][6], acc[j][7]);
  }
}

// In-place over U: G[n,c,v,t] = relu( s1[c] * (sum_v' A[v][v'] U[n,c,v',t]) + b1p[c] )
// One thread owns one (n,c,t) column of 18 joints -> in-place safe.
// A / bn params read via uniform (scalar) loads.
template <int T>
__global__ __launch_bounds__(256, 4) void k_amixg(
    float* __restrict__ U, const float* __restrict__ Amat,
    const float* __restrict__ gb, const float* __restrict__ bn1g,
    const float* __restrict__ bn1b, int CO) {
  const float rs = 1.0f / sqrtf(1.0f + EPS);
  int idx = blockIdx.x * 256 + threadIdx.x;
  int t = idx % T;            // T is a power of two (256 or 128)
  int row = idx / T;          // row = n*CO + c
  int c = row & (CO - 1);     // CO is a power of two
  float* base = U + (size_t)row * (18 * T) + t;
  float u[18];
#pragma unroll
  for (int v = 0; v < 18; v++) u[v] = base[(size_t)v * T];
  float s1 = bn1g[c] * rs;
  float b1p = fmaf(s1, gb[c], bn1b[c]);
  float g[18];
#pragma unroll
  for (int v = 0; v < 18; v++) {
    float z = 0.0f;
#pragma unroll
    for (int w = 0; w < 18; w++) z = fmaf(Amat[v * 18 + w], u[w], z);
    z = fmaf(z, s1, b1p);
    g[v] = z > 0.0f ? z : 0.0f;
  }
#pragma unroll
  for (int v = 0; v < 18; v++) base[(size_t)v * T] = g[v];
}

// Fused: residual 1x1 (strided) + 9-tap temporal conv over precomputed G
// (bn2 prescaled into twT, beta holds s2*tb+b2+rb) + final ReLU.
// G:(nc,CO,18,Tin) post A-mix/BN1/ReLU; Xin:(nc,CIN,18,Tin); Out:(nc,CO,18,Tout)
// o-tile 32 (16 og x 2 o/thread), TT=16 -> grid.z = CO/32, 4 blocks/CU.
template <int CIN, int CO, int S>
__global__ __launch_bounds__(256, 4) void k_tcn(
    const float* __restrict__ G, const float* __restrict__ Xin,
    const float* __restrict__ twT, const float* __restrict__ rwT,
    const float* __restrict__ beta, float* __restrict__ Out, int Tin, int Tout) {
  constexpr int TT = 16;
  constexpr int SPAN = (TT - 1) * S + 9;  // 24 (S=1) or 39 (S=2)
  constexpr int GSZ = (4 * SPAN * 20 > 2304) ? 4 * SPAN * 20 : 2304;
  const int n = blockIdx.x;
  const int to0 = blockIdx.y * TT;
  const int o0 = blockIdx.z * 32;
  const int og = threadIdx.x & 15;
  const int tol = threadIdx.x >> 4;
  const int o = o0 + og * 2;

  __shared__ __align__(16) float g_lds[GSZ];
  __shared__ __align__(16) float w_lds[4 * 9 * 32];

  float acc[2][18];
  {
    float b0 = beta[o], b1v = beta[o + 1];
#pragma unroll
    for (int v = 0; v < 18; v++) { acc[0][v] = b0; acc[1][v] = b1v; }
  }

  // ---- residual: acc += rw^T * Xin[:, :, S*to] ----
  const int tr0 = S * to0;
  for (int c0 = 0; c0 < CIN; c0 += 8) {
    const int cc = (CIN - c0 < 8) ? (CIN - c0) : 8;
    __syncthreads();
    for (int e = threadIdx.x; e < cc * 288; e += 256) {
      int ci = e / 288, r = e % 288;
      int v = r >> 4, tl = r & 15;
      g_lds[e] = Xin[((size_t)(n * CIN + c0 + ci) * 18 + v) * Tin + tr0 + S * tl];
    }
    for (int e = threadIdx.x; e < cc * 32; e += 256)
      w_lds[e] = rwT[(size_t)(c0 + (e >> 5)) * CO + o0 + (e & 31)];
    __syncthreads();
    for (int ci = 0; ci < cc; ci++) {
      float2 w2 = *(const float2*)&w_lds[ci * 32 + og * 2];
#pragma unroll
      for (int v = 0; v < 18; v++) {
        float xv = g_lds[ci * 288 + v * 16 + tol];
        acc[0][v] = fmaf(w2.x, xv, acc[0][v]);
        acc[1][v] = fmaf(w2.y, xv, acc[1][v]);
      }
    }
  }

  // ---- temporal conv over G ----
  const int tib = S * to0 - 4;
  for (int c0 = 0; c0 < CO; c0 += 4) {
    __syncthreads();
    // stage G chunk [4][SPAN][20] (zero outside [0,Tin)); coalesced along t
    for (int e = threadIdx.x; e < 4 * 18 * SPAN; e += 256) {
      int c = e / (18 * SPAN), r = e % (18 * SPAN);
      int v = r / SPAN, ti = r % SPAN;
      int tg = tib + ti;
      float val = 0.0f;
      if (tg >= 0 && tg < Tin)
        val = G[((size_t)(n * CO + c0 + c) * 18 + v) * Tin + tg];
      g_lds[(c * SPAN + ti) * 20 + v] = val;
    }
    // stage prescaled weights [4][9][32]
    for (int e = threadIdx.x; e < 1152; e += 256)
      w_lds[e] = twT[(size_t)(c0 * 9 + (e >> 5)) * CO + o0 + (e & 31)];
    __syncthreads();
    for (int c = 0; c < 4; c++) {
#pragma unroll
      for (int k = 0; k < 9; k++) {
        const float2 w2 = *(const float2*)&w_lds[(c * 9 + k) * 32 + og * 2];
        const float* gr = &g_lds[(c * SPAN + S * tol + k) * 20];
        const float4 ga = *(const float4*)&gr[0];
        const float4 gbv = *(const float4*)&gr[4];
        const float4 gc = *(const float4*)&gr[8];
        const float4 gd = *(const float4*)&gr[12];
        float gv[18] = {ga.x, ga.y, ga.z, ga.w, gbv.x, gbv.y, gbv.z, gbv.w,
                        gc.x, gc.y, gc.z, gc.w, gd.x, gd.y, gd.z, gd.w,
                        gr[16], gr[17]};
#pragma unroll
        for (int v = 0; v < 18; v++) {
          acc[0][v] = fmaf(w2.x, gv[v], acc[0][v]);
          acc[1][v] = fmaf(w2.y, gv[v], acc[1][v]);
        }
      }
    }
  }
#pragma unroll
  for (int j = 0; j < 2; j++)
#pragma unroll
    for (int v = 0; v < 18; v++) {
      float r = acc[j][v];
      Out[((size_t)(n * CO + o + j) * 18 + v) * Tout + to0 + tol] = r > 0.0f ? r : 0.0f;
    }
}

// in-place EMA over time; 64 rows per block, 1 wave; rows contiguous length T
__global__ __launch_bounds__(64) void k_smooth(float* __restrict__ X, int T) {
  __shared__ float tile[64 * 33];  // 8.4 KB; stride 33 -> 2-way bank alias (free)
  size_t r0 = (size_t)blockIdx.x * 64;
  float s = 0.0f;
  for (int tc = 0; tc < T; tc += 32) {
    for (int e = threadIdx.x; e < 64 * 32; e += 64) {
      int r = e >> 5, tt = e & 31;
      tile[r * 33 + tt] = X[(r0 + r) * T + tc + tt];
    }
    __syncthreads();
    float* row = &tile[threadIdx.x * 33];
    int start = 0;
    if (tc == 0) { s = row[0]; start = 1; }
    for (int tt = start; tt < 32; tt++) {
      s = fmaf(0.85f, s, 0.15f * row[tt]);
      row[tt] = s;
    }
    __syncthreads();
    for (int e = threadIdx.x; e < 64 * 32; e += 64) {
      int r = e >> 5, tt = e & 31;
      X[(r0 + r) * T + tc + tt] = tile[r * 33 + tt];
    }
    __syncthreads();
  }
}

// mean over (v,t)=1152 then 10-way FC.  H:(nc,256,18,64)
__global__ __launch_bounds__(256, 4) void k_poolfc(
    const float* __restrict__ H, const float* __restrict__ fcw,
    const float* __restrict__ fcb, float* __restrict__ out) {
  int n = blockIdx.x;
  __shared__ float pool[256];
  const float* row = H + (size_t)(n * 256 + threadIdx.x) * 1152;
  float s = 0.0f;
  for (int i = 0; i < 1152; i += 4) {
    float4 x4 = *(const float4*)&row[i];
    s += x4.x + x4.y + x4.z + x4.w;
  }
  pool[threadIdx.x] = s * (1.0f / 1152.0f);
  __syncthreads();
  if (threadIdx.x < 10) {
    float a = fcb[threadIdx.x];
    for (int c = 0; c < 256; c++) a = fmaf(fcw[threadIdx.x * 256 + c], pool[c], a);
    out[n * 10 + threadIdx.x] = a;
  }
}

extern "C" void kernel_launch(void* const* d_in, const int* in_sizes, int n_in,
                              void* d_out, int out_size, void* d_ws, size_t ws_size,
                              hipStream_t stream) {
  const float* x    = (const float*)d_in[0];
  const float* Amat = (const float*)d_in[1];
  const float* dbng = (const float*)d_in[2];
  const float* dbnb = (const float*)d_in[3];
  const float* gw1 = (const float*)d_in[4];   const float* gb1 = (const float*)d_in[5];
  const float* bn1g1 = (const float*)d_in[6]; const float* bn1b1 = (const float*)d_in[7];
  const float* tw1 = (const float*)d_in[8];   const float* tb1 = (const float*)d_in[9];
  const float* bn2g1 = (const float*)d_in[10]; const float* bn2b1 = (const float*)d_in[11];
  const float* rw1 = (const float*)d_in[12];  const float* rb1 = (const float*)d_in[13];
  const float* gw2 = (const float*)d_in[14];  const float* gb2 = (const float*)d_in[15];
  const float* bn1g2 = (const float*)d_in[16]; const float* bn1b2 = (const float*)d_in[17];
  const float* tw2 = (const float*)d_in[18];  const float* tb2 = (const float*)d_in[19];
  const float* bn2g2 = (const float*)d_in[20]; const float* bn2b2 = (const float*)d_in[21];
  const float* rw2 = (const float*)d_in[22];  const float* rb2 = (const float*)d_in[23];
  const float* gw3 = (const float*)d_in[24];  const float* gb3 = (const float*)d_in[25];
  const float* bn1g3 = (const float*)d_in[26]; const float* bn1b3 = (const float*)d_in[27];
  const float* tw3 = (const float*)d_in[28];  const float* tb3 = (const float*)d_in[29];
  const float* bn2g3 = (const float*)d_in[30]; const float* bn2b3 = (const float*)d_in[31];
  const float* rw3 = (const float*)d_in[32];  const float* rb3 = (const float*)d_in[33];
  const float* fcw = (const float*)d_in[34];  const float* fcb = (const float*)d_in[35];
  (void)in_sizes; (void)n_in; (void)out_size;

  // ---- weights region at ws base (fixed, NC-independent) ----
  float* f = (float*)d_ws;
  float* gwT2 = f;                   // 8192
  float* gwT3 = gwT2 + 8192;         // 32768
  float* rwT1 = gwT3 + 32768;        // 128
  float* rwT2 = rwT1 + 128;          // 8192
  float* rwT3 = rwT2 + 8192;         // 32768
  float* twT1 = rwT3 + 32768;        // 36864
  float* twT2 = twT1 + 36864;        // 147456
  float* twT3 = twT2 + 147456;       // 589824
  float* beta1 = twT3 + 589824;      // 64
  float* beta2 = beta1 + 64;         // 128
  float* beta3 = beta2 + 128;        // 256
  const size_t WOFF = 856832;        // weights end, aligned up to 256 floats

  // ---- pick largest chunk NC that fits ws_size ----
  int NC = 32;
  while (NC > 1 && (WOFF + (size_t)NC * 1188864ULL) * 4ULL > ws_size) NC >>= 1;
  float* Us = f + WOFF;                        // NC*589824
  float* B1 = Us + (size_t)NC * 589824;        // NC*294912
  float* B2 = B1 + (size_t)NC * 294912;        // NC*294912
  float* XB = B2 + (size_t)NC * 294912;        // NC*9216

  // ---- weight prep (idempotent, tiny) ----
  k_transpose<<<32, 256, 0, stream>>>(gw2, gwT2, 128, 64);
  k_transpose<<<128, 256, 0, stream>>>(gw3, gwT3, 256, 128);
  k_transpose<<<1, 256, 0, stream>>>(rw1, rwT1, 64, 2);
  k_transpose<<<32, 256, 0, stream>>>(rw2, rwT2, 128, 64);
  k_transpose<<<128, 256, 0, stream>>>(rw3, rwT3, 256, 128);
  k_prep_tw<<<144, 256, 0, stream>>>(tw1, bn2g1, twT1, 64);
  k_prep_tw<<<576, 256, 0, stream>>>(tw2, bn2g2, twT2, 128);
  k_prep_tw<<<2304, 256, 0, stream>>>(tw3, bn2g3, twT3, 256);
  k_beta<<<1, 256, 0, stream>>>(bn2g1, bn2b1, tb1, rb1, beta1, 64);
  k_beta<<<1, 256, 0, stream>>>(bn2g2, bn2b2, tb2, rb2, beta2, 128);
  k_beta<<<1, 256, 0, stream>>>(bn2g3, bn2b3, tb3, rb3, beta3, 256);

  // ---- whole network per N-chunk ----
  for (int n0 = 0; n0 < 128; n0 += NC) {
    // block 1
    k_front1<<<dim3(NC, 4), 256, 0, stream>>>(
        x + (size_t)n0 * 9216, dbng, dbnb, gw1, Us, XB);
    k_amixg<256><<<NC * 64, 256, 0, stream>>>(Us, Amat, gb1, bn1g1, bn1b1, 64);
    k_tcn<2, 64, 1><<<dim3(NC, 16, 2), 256, 0, stream>>>(
        Us, XB, twT1, rwT1, beta1, B1, 256, 256);
    k_smooth<<<NC * 18, 64, 0, stream>>>(B1, 256);
    // block 2
    k_ugemm<64, 128><<<dim3(NC, 36, 2), 256, 0, stream>>>(B1, gwT2, Us, 4608);
    k_amixg<256><<<NC * 128, 256, 0, stream>>>(Us, Amat, gb2, bn1g2, bn1b2, 128);
    k_tcn<64, 128, 2><<<dim3(NC, 8, 4), 256, 0, stream>>>(
        Us, B1, twT2, rwT2, beta2, B2, 256, 128);
    k_smooth<<<NC * 36, 64, 0, stream>>>(B2, 128);
    // block 3 (output reuses B1 -- dead after tcn2)
    k_ugemm<128, 256><<<dim3(NC, 18, 4), 256, 0, stream>>>(B2, gwT3, Us, 2304);
    k_amixg<128><<<NC * 128, 256, 0, stream>>>(Us, Amat, gb3, bn1g3, bn1b3, 256);
    k_tcn<128, 256, 2><<<dim3(NC, 4, 8), 256, 0, stream>>>(
        Us, B2, twT3, rwT3, beta3, B1, 128, 64);
    k_smooth<<<NC * 72, 64, 0, stream>>>(B1, 64);
    // head
    k_poolfc<<<NC, 256, 0, stream>>>(B1, fcw, fcb, (float*)d_out + (size_t)n0 * 10);
  }
}

// Round 6
// 2165.351 us; speedup vs baseline: 3.1856x; 3.1856x over previous
//
#include <hip/hip_runtime.h>
#include <hip/hip_bf16.h>

#define EPS 1e-5f

// ---------------------------------------------------------------------------
// MFMA-based ST-GCN. Layouts:
//   x   : (N,2,256,18) external
//   U   : (n, CO, 18, TIN) fp32       pre-A-mix channel-GEMM output
//   G   : (n, CO, 18, Tr=TIN+16) bf16 post A-mix/BN1/ReLU, 8-half zero guards
//   Out : (n, CO, 18, TOUT) fp32      block output (smoothed in place)
//   Xt  : (n, 18, T, CO) bf16         c-innermost copy of smoothed output
// Conv as MFMA 16x16x32 bf16: K = (c, tap k padded 9->16, k innermost) so each
// lane's 8-half K-run = 8 consecutive t of G -> direct global loads, no LDS.
// Residual 1x1 + channel GEMMs as MFMA with K=c fed from Xt (c-contiguous).
// fp32 accumulation everywhere; bf16 only in tensor storage + MFMA inputs.
// ---------------------------------------------------------------------------

typedef __attribute__((ext_vector_type(8))) short bf16x8;
typedef __attribute__((ext_vector_type(4))) float f32x4;

__device__ __forceinline__ unsigned short f2bf(float f) {
  unsigned u = __builtin_bit_cast(unsigned, f);
  u = (u + 0x7FFFu + ((u >> 16) & 1u)) >> 16;  // RNE, finite inputs
  return (unsigned short)u;
}

// --------------------------- weight prep -----------------------------------

__global__ __launch_bounds__(256, 4) void k_transpose(
    const float* __restrict__ in, float* __restrict__ out, int rows, int cols) {
  int i = blockIdx.x * 256 + threadIdx.x;
  if (i < rows * cols) {
    int r = i / cols, c = i % cols;
    out[c * rows + r] = in[i];
  }
}

// beta[o] = s2*tb + b2 + rb
__global__ __launch_bounds__(256, 4) void k_beta(
    const float* __restrict__ bn2g, const float* __restrict__ bn2b,
    const float* __restrict__ tb, const float* __restrict__ rb,
    float* __restrict__ beta, int Co) {
  int o = blockIdx.x * 256 + threadIdx.x;
  if (o < Co)
    beta[o] = bn2g[o] * (1.0f / sqrtf(1.0f + EPS)) * tb[o] + bn2b[o] + rb[o];
}

// Conv A pack: out[ot][kc][lane][8], K-chunk = 2c x 16k (k innermost, pad 9->16)
// A[m=lane&15=o_local][k_local=q*8+j]; c = kc*2+(q>>1), tap = (q&1)*8+j
__global__ __launch_bounds__(256, 4) void k_pack_conv(
    const float* __restrict__ tw, const float* __restrict__ bn2g,
    unsigned short* __restrict__ out, int CO) {
  int total = (CO / 16) * (CO / 2) * 512;
  int i = blockIdx.x * 256 + threadIdx.x;
  if (i >= total) return;
  int j = i & 7, lane = (i >> 3) & 63, rest = i >> 9;
  int kc = rest % (CO / 2), ot = rest / (CO / 2);
  int q = lane >> 4, m = lane & 15;
  int c = kc * 2 + (q >> 1), k = (q & 1) * 8 + j, o = ot * 16 + m;
  float val = 0.0f;
  if (k < 9)
    val = tw[((size_t)o * CO + c) * 9 + k] * bn2g[o] * (1.0f / sqrtf(1.0f + EPS));
  out[i] = f2bf(val);
}

// K=c pack (residual rw / channel gw): out[ot][kc][lane][8], c = kc*32+q*8+j
__global__ __launch_bounds__(256, 4) void k_pack_k32(
    const float* __restrict__ W, unsigned short* __restrict__ out, int K, int M) {
  int total = (M / 16) * (K / 32) * 512;
  int i = blockIdx.x * 256 + threadIdx.x;
  if (i >= total) return;
  int j = i & 7, lane = (i >> 3) & 63, rest = i >> 9;
  int kc = rest % (K / 32), ot = rest / (K / 32);
  int q = lane >> 4, m = lane & 15;
  int c = kc * 32 + q * 8 + j, o = ot * 16 + m;
  out[i] = f2bf(W[(size_t)o * K + c]);
}

// --------------------------- block 1 front ---------------------------------
// data_bn + 1x1 (Ci=2) -> U1 (n,64,18,256) fp32; also XB (n,2,18,256) fp32
__global__ __launch_bounds__(256, 4) void k_front1(
    const float* __restrict__ x, const float* __restrict__ dbng,
    const float* __restrict__ dbnb, const float* __restrict__ gw,
    float* __restrict__ U1, float* __restrict__ xb1) {
  int n = blockIdx.x, t0 = blockIdx.y * 64;
  __shared__ float xb[2 * 64 * 18];  // [c][tt][v]
  const float rs = 1.0f / sqrtf(1.0f + EPS);
  for (int e = threadIdx.x; e < 2304; e += 256) {
    int c = e / 1152, r = e % 1152;  // r = tt*18+v
    int v = r % 18;
    xb[e] = x[(n * 2 + c) * 4608 + t0 * 18 + r] * (dbng[c * 18 + v] * rs) + dbnb[c * 18 + v];
  }
  __syncthreads();
  for (int e = threadIdx.x; e < 2304; e += 256) {
    int c = e / 1152, r = e % 1152;
    int v = r / 64, tt = r % 64;
    xb1[((size_t)(n * 2 + c) * 18 + v) * 256 + t0 + tt] = xb[c * 1152 + tt * 18 + v];
  }
  for (int e = threadIdx.x; e < 64 * 1152; e += 256) {
    int o = e / 1152, r = e % 1152;
    int v = r / 64, tt = r % 64;
    float g0 = gw[o * 2 + 0], g1 = gw[o * 2 + 1];
    U1[((size_t)(n * 64 + o) * 18 + v) * 256 + t0 + tt] =
        fmaf(g0, xb[tt * 18 + v], g1 * xb[1152 + tt * 18 + v]);
  }
}

// --------------------------- channel GEMM (MFMA) ---------------------------
// U[n,o,p] = sum_c gw[o,c] * Xt[n,p,c];  p = v*T+t, NP = 18*T (mult of 32)
template <int CI, int CO>
__global__ __launch_bounds__(64, 4) void k_ugemm_m(
    const unsigned short* __restrict__ Xt, const unsigned short* __restrict__ Ag,
    float* __restrict__ U, int NP) {
  const int n = blockIdx.x;
  const int p0 = blockIdx.y * 32;
  const int otg = blockIdx.z;  // 2 o-tiles of 16
  const int lane = threadIdx.x;
  const int q = lane >> 4, nn = lane & 15;
  constexpr int KC = CI / 32;
  f32x4 acc[2][2] = {};
  const unsigned short* Xn = Xt + (size_t)n * NP * CI;
  for (int kc = 0; kc < KC; kc++) {
    bf16x8 A[2];
#pragma unroll
    for (int i = 0; i < 2; i++)
      A[i] = *(const bf16x8*)(Ag + (((size_t)(otg * 2 + i) * KC + kc) * 64 + lane) * 8);
#pragma unroll
    for (int u = 0; u < 2; u++) {
      bf16x8 B = *(const bf16x8*)(Xn + (size_t)(p0 + u * 16 + nn) * CI + kc * 32 + q * 8);
#pragma unroll
      for (int i = 0; i < 2; i++)
        acc[i][u] = __builtin_amdgcn_mfma_f32_16x16x32_bf16(A[i], B, acc[i][u], 0, 0, 0);
    }
  }
#pragma unroll
  for (int i = 0; i < 2; i++)
#pragma unroll
    for (int u = 0; u < 2; u++) {
      int ob = (otg * 2 + i) * 16 + q * 4;
      int p = p0 + u * 16 + nn;
#pragma unroll
      for (int r = 0; r < 4; r++)
        U[((size_t)n * CO + ob + r) * NP + p] = acc[i][u][r];
    }
}

// --------------------------- A-mix + BN1 + ReLU -> G bf16 ------------------
// one thread per (n,c,t) column of 18 joints; writes guarded bf16 rows.
template <int TIN>
__global__ __launch_bounds__(256, 4) void k_amixg(
    const float* __restrict__ U, unsigned short* __restrict__ G,
    const float* __restrict__ Amat, const float* __restrict__ gb,
    const float* __restrict__ bn1g, const float* __restrict__ bn1b, int CO) {
  constexpr int Tr = TIN + 16;
  const float rs = 1.0f / sqrtf(1.0f + EPS);
  int idx = blockIdx.x * 256 + threadIdx.x;
  int t = idx & (TIN - 1);
  int row = idx / TIN;        // n*CO + c
  int c = row & (CO - 1);     // CO pow2
  const float* base = U + (size_t)row * (18 * TIN) + t;
  float u[18];
#pragma unroll
  for (int v = 0; v < 18; v++) u[v] = base[(size_t)v * TIN];
  float s1 = bn1g[c] * rs;
  float b1p = fmaf(s1, gb[c], bn1b[c]);
  unsigned short* gbase = G + (size_t)row * 18 * Tr;
#pragma unroll
  for (int v = 0; v < 18; v++) {
    float z = 0.0f;
#pragma unroll
    for (int w = 0; w < 18; w++) z = fmaf(Amat[v * 18 + w], u[w], z);
    z = fmaf(z, s1, b1p);
    z = z > 0.0f ? z : 0.0f;
    gbase[v * Tr + 8 + t] = f2bf(z);
    if (t < 8) gbase[v * Tr + t] = 0;
    if (t >= TIN - 8) gbase[v * Tr + t + 16] = 0;
  }
}

// --------------------------- fused conv (MFMA) -----------------------------
// Out[o,v,to] = relu( beta[o] + sum_{c,k<9} tw's[o,c,k] G[c,v,S*to+k-4]
//                              + sum_c rw[o,c] Xin[c,v,S*to] )
// one wave per block; OTB o-tiles x 2 v per wave.
template <int CIN, int CO, int S, int TIN, int TOUT, int OTB>
__global__ __launch_bounds__(64, 4) void k_conv(
    const unsigned short* __restrict__ G, const unsigned short* __restrict__ Xt,
    const float* __restrict__ XB, const unsigned short* __restrict__ Ac,
    const unsigned short* __restrict__ Ar, const float* __restrict__ rwT1,
    const float* __restrict__ beta, float* __restrict__ Out) {
  constexpr int Tr = TIN + 16;
  constexpr int KC = CO / 2;
  constexpr int KCR = (CIN >= 32) ? CIN / 32 : 0;
  constexpr int OT2 = CO / (16 * OTB);
  const int n = blockIdx.x;
  const int to0 = blockIdx.y * 16;
  const int z = blockIdx.z;
  const int otg = z % OT2;
  const int v0 = (z / OT2) * 2;
  const int lane = threadIdx.x;
  const int q = lane >> 4, nn = lane & 15;
  const int cq = q >> 1, kh = q & 1;

  f32x4 acc[OTB][2] = {};

  const unsigned* Gu = (const unsigned*)G;
  const int t0h = S * (to0 + nn) - 4 + kh * 8;
  // half offsets per u, for c = cq (kc=0); advance by 2*18*Tr per kc
  size_t h_u[2];
#pragma unroll
  for (int u = 0; u < 2; u++)
    h_u[u] = ((size_t)n * CO + cq) * (18 * Tr) + (size_t)(v0 + u) * Tr + 8 + (size_t)(long)t0h;

  const unsigned short* Acp = Ac + ((size_t)otg * OTB * KC * 64 + lane) * 8;
  for (int kc = 0; kc < KC; kc++) {
    bf16x8 A[OTB];
#pragma unroll
    for (int i = 0; i < OTB; i++)
      A[i] = *(const bf16x8*)(Acp + ((size_t)i * KC + kc) * 512);
#pragma unroll
    for (int u = 0; u < 2; u++) {
      size_t h = h_u[u] + (size_t)kc * (2 * 18 * Tr);
      union { unsigned d[4]; bf16x8 v; } bb;
      if (S == 2) {
        const unsigned* p = Gu + (h >> 1);
        bb.d[0] = p[0]; bb.d[1] = p[1]; bb.d[2] = p[2]; bb.d[3] = p[3];
      } else {
        const unsigned* p = Gu + (h >> 1);
        unsigned d0 = p[0], d1 = p[1], d2 = p[2], d3 = p[3], d4 = p[4];
        if (h & 1) {
          bb.d[0] = (d0 >> 16) | (d1 << 16); bb.d[1] = (d1 >> 16) | (d2 << 16);
          bb.d[2] = (d2 >> 16) | (d3 << 16); bb.d[3] = (d3 >> 16) | (d4 << 16);
        } else {
          bb.d[0] = d0; bb.d[1] = d1; bb.d[2] = d2; bb.d[3] = d3;
        }
      }
#pragma unroll
      for (int i = 0; i < OTB; i++)
        acc[i][u] = __builtin_amdgcn_mfma_f32_16x16x32_bf16(A[i], bb.v, acc[i][u], 0, 0, 0);
    }
  }

  if (CIN >= 32) {
    // residual via MFMA from c-innermost Xt
    for (int kcr = 0; kcr < KCR; kcr++) {
      bf16x8 A[OTB];
#pragma unroll
      for (int i = 0; i < OTB; i++)
        A[i] = *(const bf16x8*)(Ar + (((size_t)(otg * OTB + i) * KCR + kcr) * 64 + lane) * 8);
#pragma unroll
      for (int u = 0; u < 2; u++) {
        int t = S * (to0 + nn);
        bf16x8 B = *(const bf16x8*)(Xt + (((size_t)n * 18 + v0 + u) * TIN + t) * CIN +
                                    kcr * 32 + q * 8);
#pragma unroll
        for (int i = 0; i < OTB; i++)
          acc[i][u] = __builtin_amdgcn_mfma_f32_16x16x32_bf16(A[i], B, acc[i][u], 0, 0, 0);
      }
    }
  } else {
    // block-1 residual: CIN=2 fp32 VALU from XB
#pragma unroll
    for (int ci = 0; ci < 2; ci++) {
#pragma unroll
      for (int u = 0; u < 2; u++) {
        float xv = XB[(((size_t)n * 2 + ci) * 18 + v0 + u) * TIN + S * (to0 + nn)];
#pragma unroll
        for (int i = 0; i < OTB; i++) {
          const float4 w4 = *(const float4*)&rwT1[ci * CO + (otg * OTB + i) * 16 + q * 4];
          acc[i][u][0] = fmaf(w4.x, xv, acc[i][u][0]);
          acc[i][u][1] = fmaf(w4.y, xv, acc[i][u][1]);
          acc[i][u][2] = fmaf(w4.z, xv, acc[i][u][2]);
          acc[i][u][3] = fmaf(w4.w, xv, acc[i][u][3]);
        }
      }
    }
  }

#pragma unroll
  for (int i = 0; i < OTB; i++) {
    int ob = (otg * OTB + i) * 16 + q * 4;
    const float4 bt = *(const float4*)&beta[ob];
#pragma unroll
    for (int u = 0; u < 2; u++) {
      int v = v0 + u, to = to0 + nn;
#pragma unroll
      for (int r = 0; r < 4; r++) {
        float val = acc[i][u][r] + ((const float*)&bt)[r];
        Out[(((size_t)n * CO + ob + r) * 18 + v) * TOUT + to] = val > 0.0f ? val : 0.0f;
      }
    }
  }
}

// ------------------ EMA smooth + bf16 transposed emission ------------------
// grid (NC, 18, CO/64); block 64. X (n,CO,18,T) fp32 in-place; Xt (n,18,T,CO) bf16.
__global__ __launch_bounds__(64) void k_smooth2(
    float* __restrict__ X, unsigned short* __restrict__ Xt, int CO, int T) {
  __shared__ float tile[64 * 33];
  int n = blockIdx.x, v = blockIdx.y, c0 = blockIdx.z * 64;
  int tid = threadIdx.x;
  float s = 0.0f;
  for (int tc = 0; tc < T; tc += 32) {
    for (int e = tid; e < 64 * 32; e += 64) {
      int cc = e >> 5, tt = e & 31;
      tile[cc * 33 + tt] = X[((size_t)(n * CO + c0 + cc) * 18 + v) * T + tc + tt];
    }
    __syncthreads();
    float* row = &tile[tid * 33];
    int start = 0;
    if (tc == 0) { s = row[0]; start = 1; }
    for (int tt = start; tt < 32; tt++) {
      s = fmaf(0.85f, s, 0.15f * row[tt]);
      row[tt] = s;
    }
    __syncthreads();
    for (int e = tid; e < 64 * 32; e += 64) {
      int cc = e >> 5, tt = e & 31;
      X[((size_t)(n * CO + c0 + cc) * 18 + v) * T + tc + tt] = tile[cc * 33 + tt];
    }
    for (int it = 0; it < 32; it++)
      Xt[((size_t)(n * 18 + v) * T + tc + it) * CO + c0 + tid] = f2bf(tile[tid * 33 + it]);
    __syncthreads();
  }
}

// plain in-place EMA (final block; no Xt needed). rows contiguous length T.
__global__ __launch_bounds__(64) void k_smooth(float* __restrict__ X, int T) {
  __shared__ float tile[64 * 33];
  size_t r0 = (size_t)blockIdx.x * 64;
  float s = 0.0f;
  for (int tc = 0; tc < T; tc += 32) {
    for (int e = threadIdx.x; e < 64 * 32; e += 64) {
      int r = e >> 5, tt = e & 31;
      tile[r * 33 + tt] = X[(r0 + r) * T + tc + tt];
    }
    __syncthreads();
    float* row = &tile[threadIdx.x * 33];
    int start = 0;
    if (tc == 0) { s = row[0]; start = 1; }
    for (int tt = start; tt < 32; tt++) {
      s = fmaf(0.85f, s, 0.15f * row[tt]);
      row[tt] = s;
    }
    __syncthreads();
    for (int e = threadIdx.x; e < 64 * 32; e += 64) {
      int r = e >> 5, tt = e & 31;
      X[(r0 + r) * T + tc + tt] = tile[r * 33 + tt];
    }
    __syncthreads();
  }
}

// mean over (v,t)=1152 then 10-way FC.  H:(nc,256,18,64)
__global__ __launch_bounds__(256, 4) void k_poolfc(
    const float* __restrict__ H, const float* __restrict__ fcw,
    const float* __restrict__ fcb, float* __restrict__ out) {
  int n = blockIdx.x;
  __shared__ float pool[256];
  const float* row = H + (size_t)(n * 256 + threadIdx.x) * 1152;
  float s = 0.0f;
  for (int i = 0; i < 1152; i += 4) {
    float4 x4 = *(const float4*)&row[i];
    s += x4.x + x4.y + x4.z + x4.w;
  }
  pool[threadIdx.x] = s * (1.0f / 1152.0f);
  __syncthreads();
  if (threadIdx.x < 10) {
    float a = fcb[threadIdx.x];
    for (int c = 0; c < 256; c++) a = fmaf(fcw[threadIdx.x * 256 + c], pool[c], a);
    out[n * 10 + threadIdx.x] = a;
  }
}

extern "C" void kernel_launch(void* const* d_in, const int* in_sizes, int n_in,
                              void* d_out, int out_size, void* d_ws, size_t ws_size,
                              hipStream_t stream) {
  const float* x    = (const float*)d_in[0];
  const float* Amat = (const float*)d_in[1];
  const float* dbng = (const float*)d_in[2];
  const float* dbnb = (const float*)d_in[3];
  const float* gw1 = (const float*)d_in[4];   const float* gb1 = (const float*)d_in[5];
  const float* bn1g1 = (const float*)d_in[6]; const float* bn1b1 = (const float*)d_in[7];
  const float* tw1 = (const float*)d_in[8];   const float* tb1 = (const float*)d_in[9];
  const float* bn2g1 = (const float*)d_in[10]; const float* bn2b1 = (const float*)d_in[11];
  const float* rw1 = (const float*)d_in[12];  const float* rb1 = (const float*)d_in[13];
  const float* gw2 = (const float*)d_in[14];  const float* gb2 = (const float*)d_in[15];
  const float* bn1g2 = (const float*)d_in[16]; const float* bn1b2 = (const float*)d_in[17];
  const float* tw2 = (const float*)d_in[18];  const float* tb2 = (const float*)d_in[19];
  const float* bn2g2 = (const float*)d_in[20]; const float* bn2b2 = (const float*)d_in[21];
  const float* rw2 = (const float*)d_in[22];  const float* rb2 = (const float*)d_in[23];
  const float* gw3 = (const float*)d_in[24];  const float* gb3 = (const float*)d_in[25];
  const float* bn1g3 = (const float*)d_in[26]; const float* bn1b3 = (const float*)d_in[27];
  const float* tw3 = (const float*)d_in[28];  const float* tb3 = (const float*)d_in[29];
  const float* bn2g3 = (const float*)d_in[30]; const float* bn2b3 = (const float*)d_in[31];
  const float* rw3 = (const float*)d_in[32];  const float* rb3 = (const float*)d_in[33];
  const float* fcw = (const float*)d_in[34];  const float* fcb = (const float*)d_in[35];
  (void)in_sizes; (void)n_in; (void)out_size;

  // ---- weights region at ws base ----
  float* f = (float*)d_ws;
  float* rwT1  = f;             // 128
  float* beta1 = rwT1 + 128;    // 64
  float* beta2 = beta1 + 64;    // 128
  float* beta3 = beta2 + 128;   // 256
  // pad to 1024 floats
  unsigned short* H = (unsigned short*)(f + 1024);
  unsigned short* Ac1 = H;                 // 65536
  unsigned short* Ac2 = Ac1 + 65536;       // 262144
  unsigned short* Ac3 = Ac2 + 262144;      // 1048576
  unsigned short* Ar2 = Ac3 + 1048576;     // 8192
  unsigned short* Ar3 = Ar2 + 8192;        // 32768
  unsigned short* Ag2 = Ar3 + 32768;       // 8192
  unsigned short* Ag3 = Ag2 + 8192;        // 32768
  const size_t WOFFB = 4096 + 1458176ULL * 2;  // 2,920,448 bytes

  // ---- pick largest chunk NC that fits ws_size ----
  // per-n: U 2359296 + B1/B2 2*1179648 + XB 36864 (fp32 bytes)
  //        + G 663552*2 + Xt 294912*2 (bf16 bytes) = 6,672,384 B
  int NC = 32;
  while (NC > 1 && WOFFB + (size_t)NC * 6672384ULL + 64 > ws_size) NC >>= 1;
  float* U  = f + (WOFFB / 4);
  float* B1 = U + (size_t)NC * 589824;
  float* B2 = B1 + (size_t)NC * 294912;
  float* XB = B2 + (size_t)NC * 294912;
  unsigned short* G  = (unsigned short*)(XB + (size_t)NC * 9216);
  unsigned short* Xt = G + (size_t)NC * 663552 + 16;

  // ---- weight prep (idempotent) ----
  k_transpose<<<1, 256, 0, stream>>>(rw1, rwT1, 64, 2);
  k_beta<<<1, 256, 0, stream>>>(bn2g1, bn2b1, tb1, rb1, beta1, 64);
  k_beta<<<1, 256, 0, stream>>>(bn2g2, bn2b2, tb2, rb2, beta2, 128);
  k_beta<<<1, 256, 0, stream>>>(bn2g3, bn2b3, tb3, rb3, beta3, 256);
  k_pack_conv<<<256, 256, 0, stream>>>(tw1, bn2g1, Ac1, 64);
  k_pack_conv<<<1024, 256, 0, stream>>>(tw2, bn2g2, Ac2, 128);
  k_pack_conv<<<4096, 256, 0, stream>>>(tw3, bn2g3, Ac3, 256);
  k_pack_k32<<<32, 256, 0, stream>>>(rw2, Ar2, 64, 128);
  k_pack_k32<<<128, 256, 0, stream>>>(rw3, Ar3, 128, 256);
  k_pack_k32<<<32, 256, 0, stream>>>(gw2, Ag2, 64, 128);
  k_pack_k32<<<128, 256, 0, stream>>>(gw3, Ag3, 128, 256);

  // ---- network per N-chunk ----
  for (int n0 = 0; n0 < 128; n0 += NC) {
    // block 1
    k_front1<<<dim3(NC, 4), 256, 0, stream>>>(
        x + (size_t)n0 * 9216, dbng, dbnb, gw1, U, XB);
    k_amixg<256><<<NC * 64, 256, 0, stream>>>(U, G, Amat, gb1, bn1g1, bn1b1, 64);
    k_conv<2, 64, 1, 256, 256, 4><<<dim3(NC, 16, 9), 64, 0, stream>>>(
        G, nullptr, XB, Ac1, nullptr, rwT1, beta1, B1);
    k_smooth2<<<dim3(NC, 18, 1), 64, 0, stream>>>(B1, Xt, 64, 256);
    // block 2
    k_ugemm_m<64, 128><<<dim3(NC, 144, 4), 64, 0, stream>>>(Xt, Ag2, U, 4608);
    k_amixg<256><<<NC * 128, 256, 0, stream>>>(U, G, Amat, gb2, bn1g2, bn1b2, 128);
    k_conv<64, 128, 2, 256, 128, 4><<<dim3(NC, 8, 18), 64, 0, stream>>>(
        G, Xt, nullptr, Ac2, Ar2, nullptr, beta2, B2);
    k_smooth2<<<dim3(NC, 18, 2), 64, 0, stream>>>(B2, Xt, 128, 128);
    // block 3 (output reuses B1)
    k_ugemm_m<128, 256><<<dim3(NC, 72, 8), 64, 0, stream>>>(Xt, Ag3, U, 2304);
    k_amixg<128><<<NC * 128, 256, 0, stream>>>(U, G, Amat, gb3, bn1g3, bn1b3, 256);
    k_conv<128, 256, 2, 128, 64, 4><<<dim3(NC, 4, 36), 64, 0, stream>>>(
        G, Xt, nullptr, Ac3, Ar3, nullptr, beta3, B1);
    k_smooth<<<NC * 72, 64, 0, stream>>>(B1, 64);
    // head
    k_poolfc<<<NC, 256, 0, stream>>>(B1, fcw, fcb, (float*)d_out + (size_t)n0 * 10);
  }
}

// Round 7
// 2056.262 us; speedup vs baseline: 3.3546x; 1.0531x over previous
//
#include <hip/hip_runtime.h>
#include <hip/hip_bf16.h>

#define EPS 1e-5f

// ---------------------------------------------------------------------------
// MFMA-based ST-GCN. Layouts:
//   x   : (N,2,256,18) external
//   U   : (n, CO, 18, TIN) fp32       pre-A-mix channel-GEMM output
//   G   : (n, CO, 18, Tr=TIN+16) bf16 post A-mix/BN1/ReLU, 8-half zero guards
//   Out : (n, CO, 18, TOUT) fp32      block output (smoothed in place)
//   Xt  : (n, 18, T, CO) bf16         c-innermost copy of smoothed output
// Conv as MFMA 16x16x32 bf16: K = (c, tap k padded 9->16, k innermost) so each
// lane's 8-half K-run = 8 consecutive t of G -> direct global loads, no LDS.
// k_conv tiles OTB=4 o-tiles x TB=2 to-tiles x 2 v per wave: weights reused
// across TB*2v outputs, B reused across OTB -> L2 traffic halved vs R6 and
// 12 independent loads in flight per kc step (latency hiding).
// Residual 1x1 + channel GEMMs as MFMA with K=c fed from Xt (c-contiguous).
// fp32 accumulation everywhere; bf16 only in tensor storage + MFMA inputs.
// ---------------------------------------------------------------------------

typedef __attribute__((ext_vector_type(8))) short bf16x8;
typedef __attribute__((ext_vector_type(4))) float f32x4;

__device__ __forceinline__ unsigned short f2bf(float f) {
  unsigned u = __builtin_bit_cast(unsigned, f);
  u = (u + 0x7FFFu + ((u >> 16) & 1u)) >> 16;  // RNE, finite inputs
  return (unsigned short)u;
}

// --------------------------- weight prep -----------------------------------

__global__ __launch_bounds__(256, 4) void k_transpose(
    const float* __restrict__ in, float* __restrict__ out, int rows, int cols) {
  int i = blockIdx.x * 256 + threadIdx.x;
  if (i < rows * cols) {
    int r = i / cols, c = i % cols;
    out[c * rows + r] = in[i];
  }
}

// beta[o] = s2*tb + b2 + rb
__global__ __launch_bounds__(256, 4) void k_beta(
    const float* __restrict__ bn2g, const float* __restrict__ bn2b,
    const float* __restrict__ tb, const float* __restrict__ rb,
    float* __restrict__ beta, int Co) {
  int o = blockIdx.x * 256 + threadIdx.x;
  if (o < Co)
    beta[o] = bn2g[o] * (1.0f / sqrtf(1.0f + EPS)) * tb[o] + bn2b[o] + rb[o];
}

// Conv A pack: out[ot][kc][lane][8], K-chunk = 2c x 16k (k innermost, pad 9->16)
// A[m=lane&15=o_local][k_local=q*8+j]; c = kc*2+(q>>1), tap = (q&1)*8+j
__global__ __launch_bounds__(256, 4) void k_pack_conv(
    const float* __restrict__ tw, const float* __restrict__ bn2g,
    unsigned short* __restrict__ out, int CO) {
  int total = (CO / 16) * (CO / 2) * 512;
  int i = blockIdx.x * 256 + threadIdx.x;
  if (i >= total) return;
  int j = i & 7, lane = (i >> 3) & 63, rest = i >> 9;
  int kc = rest % (CO / 2), ot = rest / (CO / 2);
  int q = lane >> 4, m = lane & 15;
  int c = kc * 2 + (q >> 1), k = (q & 1) * 8 + j, o = ot * 16 + m;
  float val = 0.0f;
  if (k < 9)
    val = tw[((size_t)o * CO + c) * 9 + k] * bn2g[o] * (1.0f / sqrtf(1.0f + EPS));
  out[i] = f2bf(val);
}

// K=c pack (residual rw / channel gw): out[ot][kc][lane][8], c = kc*32+q*8+j
__global__ __launch_bounds__(256, 4) void k_pack_k32(
    const float* __restrict__ W, unsigned short* __restrict__ out, int K, int M) {
  int total = (M / 16) * (K / 32) * 512;
  int i = blockIdx.x * 256 + threadIdx.x;
  if (i >= total) return;
  int j = i & 7, lane = (i >> 3) & 63, rest = i >> 9;
  int kc = rest % (K / 32), ot = rest / (K / 32);
  int q = lane >> 4, m = lane & 15;
  int c = kc * 32 + q * 8 + j, o = ot * 16 + m;
  out[i] = f2bf(W[(size_t)o * K + c]);
}

// --------------------------- block 1 front ---------------------------------
// data_bn + 1x1 (Ci=2) -> U1 (n,64,18,256) fp32; also XB (n,2,18,256) fp32
__global__ __launch_bounds__(256, 4) void k_front1(
    const float* __restrict__ x, const float* __restrict__ dbng,
    const float* __restrict__ dbnb, const float* __restrict__ gw,
    float* __restrict__ U1, float* __restrict__ xb1) {
  int n = blockIdx.x, t0 = blockIdx.y * 64;
  __shared__ float xb[2 * 64 * 18];  // [c][tt][v]
  const float rs = 1.0f / sqrtf(1.0f + EPS);
  for (int e = threadIdx.x; e < 2304; e += 256) {
    int c = e / 1152, r = e % 1152;  // r = tt*18+v
    int v = r % 18;
    xb[e] = x[(n * 2 + c) * 4608 + t0 * 18 + r] * (dbng[c * 18 + v] * rs) + dbnb[c * 18 + v];
  }
  __syncthreads();
  for (int e = threadIdx.x; e < 2304; e += 256) {
    int c = e / 1152, r = e % 1152;
    int v = r / 64, tt = r % 64;
    xb1[((size_t)(n * 2 + c) * 18 + v) * 256 + t0 + tt] = xb[c * 1152 + tt * 18 + v];
  }
  for (int e = threadIdx.x; e < 64 * 1152; e += 256) {
    int o = e / 1152, r = e % 1152;
    int v = r / 64, tt = r % 64;
    float g0 = gw[o * 2 + 0], g1 = gw[o * 2 + 1];
    U1[((size_t)(n * 64 + o) * 18 + v) * 256 + t0 + tt] =
        fmaf(g0, xb[tt * 18 + v], g1 * xb[1152 + tt * 18 + v]);
  }
}

// --------------------------- channel GEMM (MFMA) ---------------------------
// U[n,o,p] = sum_c gw[o,c] * Xt[n,p,c];  p = v*T+t, NP = 18*T (mult of 32)
template <int CI, int CO>
__global__ __launch_bounds__(64, 4) void k_ugemm_m(
    const unsigned short* __restrict__ Xt, const unsigned short* __restrict__ Ag,
    float* __restrict__ U, int NP) {
  const int n = blockIdx.x;
  const int p0 = blockIdx.y * 32;
  const int otg = blockIdx.z;  // 2 o-tiles of 16
  const int lane = threadIdx.x;
  const int q = lane >> 4, nn = lane & 15;
  constexpr int KC = CI / 32;
  f32x4 acc[2][2] = {};
  const unsigned short* Xn = Xt + (size_t)n * NP * CI;
  for (int kc = 0; kc < KC; kc++) {
    bf16x8 A[2];
#pragma unroll
    for (int i = 0; i < 2; i++)
      A[i] = *(const bf16x8*)(Ag + (((size_t)(otg * 2 + i) * KC + kc) * 64 + lane) * 8);
#pragma unroll
    for (int u = 0; u < 2; u++) {
      bf16x8 B = *(const bf16x8*)(Xn + (size_t)(p0 + u * 16 + nn) * CI + kc * 32 + q * 8);
#pragma unroll
      for (int i = 0; i < 2; i++)
        acc[i][u] = __builtin_amdgcn_mfma_f32_16x16x32_bf16(A[i], B, acc[i][u], 0, 0, 0);
    }
  }
#pragma unroll
  for (int i = 0; i < 2; i++)
#pragma unroll
    for (int u = 0; u < 2; u++) {
      int ob = (otg * 2 + i) * 16 + q * 4;
      int p = p0 + u * 16 + nn;
#pragma unroll
      for (int r = 0; r < 4; r++)
        U[((size_t)n * CO + ob + r) * NP + p] = acc[i][u][r];
    }
}

// --------------------------- A-mix + BN1 + ReLU -> G bf16 ------------------
// one thread per (n,c,t) column of 18 joints; writes guarded bf16 rows.
template <int TIN>
__global__ __launch_bounds__(256, 4) void k_amixg(
    const float* __restrict__ U, unsigned short* __restrict__ G,
    const float* __restrict__ Amat, const float* __restrict__ gb,
    const float* __restrict__ bn1g, const float* __restrict__ bn1b, int CO) {
  constexpr int Tr = TIN + 16;
  const float rs = 1.0f / sqrtf(1.0f + EPS);
  int idx = blockIdx.x * 256 + threadIdx.x;
  int t = idx & (TIN - 1);
  int row = idx / TIN;        // n*CO + c
  int c = row & (CO - 1);     // CO pow2
  const float* base = U + (size_t)row * (18 * TIN) + t;
  float u[18];
#pragma unroll
  for (int v = 0; v < 18; v++) u[v] = base[(size_t)v * TIN];
  float s1 = bn1g[c] * rs;
  float b1p = fmaf(s1, gb[c], bn1b[c]);
  unsigned short* gbase = G + (size_t)row * 18 * Tr;
#pragma unroll
  for (int v = 0; v < 18; v++) {
    float z = 0.0f;
#pragma unroll
    for (int w = 0; w < 18; w++) z = fmaf(Amat[v * 18 + w], u[w], z);
    z = fmaf(z, s1, b1p);
    z = z > 0.0f ? z : 0.0f;
    gbase[v * Tr + 8 + t] = f2bf(z);
    if (t < 8) gbase[v * Tr + t] = 0;
    if (t >= TIN - 8) gbase[v * Tr + t + 16] = 0;
  }
}

// --------------------------- fused conv (MFMA) -----------------------------
// Out[o,v,to] = relu( beta[o] + sum_{c,k<9} tw's[o,c,k] G[c,v,S*to+k-4]
//                              + sum_c rw[o,c] Xin[c,v,S*to] )
// one wave per block; OTB o-tiles x TB to-tiles x 2 v per wave.
template <int CIN, int CO, int S, int TIN, int TOUT, int OTB, int TB>
__global__ __launch_bounds__(64, 4) void k_conv(
    const unsigned short* __restrict__ G, const unsigned short* __restrict__ Xt,
    const float* __restrict__ XB, const unsigned short* __restrict__ Ac,
    const unsigned short* __restrict__ Ar, const float* __restrict__ rwT1,
    const float* __restrict__ beta, float* __restrict__ Out) {
  constexpr int Tr = TIN + 16;
  constexpr int KC = CO / 2;
  constexpr int KCR = (CIN >= 32) ? CIN / 32 : 0;
  constexpr int OT2 = CO / (16 * OTB);
  const int n = blockIdx.x;
  const int to_base = blockIdx.y * (16 * TB);
  const int z = blockIdx.z;
  const int otg = z % OT2;
  const int v0 = (z / OT2) * 2;
  const int lane = threadIdx.x;
  const int q = lane >> 4, nn = lane & 15;
  const int cq = q >> 1, kh = q & 1;

  f32x4 acc[OTB][TB][2] = {};

  const unsigned* Gu = (const unsigned*)G;
  // half offsets per (tb,u) for c = cq (kc=0); advance by 2*18*Tr per kc
  size_t h_tu[TB][2];
#pragma unroll
  for (int tb = 0; tb < TB; tb++)
#pragma unroll
    for (int u = 0; u < 2; u++) {
      int t0h = S * (to_base + tb * 16 + nn) - 4 + kh * 8;
      h_tu[tb][u] = ((size_t)n * CO + cq) * (18 * Tr) + (size_t)(v0 + u) * Tr + 8 +
                    (size_t)(long)t0h;
    }

  const unsigned short* Acp = Ac + ((size_t)otg * OTB * KC * 64 + lane) * 8;
  for (int kc = 0; kc < KC; kc++) {
    bf16x8 A[OTB];
#pragma unroll
    for (int i = 0; i < OTB; i++)
      A[i] = *(const bf16x8*)(Acp + ((size_t)i * KC + kc) * 512);
    bf16x8 B[TB][2];
#pragma unroll
    for (int tb = 0; tb < TB; tb++)
#pragma unroll
      for (int u = 0; u < 2; u++) {
        size_t h = h_tu[tb][u] + (size_t)kc * (2 * 18 * Tr);
        union { unsigned d[4]; bf16x8 v; } bb;
        if (S == 2) {
          const unsigned* p = Gu + (h >> 1);
          bb.d[0] = p[0]; bb.d[1] = p[1]; bb.d[2] = p[2]; bb.d[3] = p[3];
        } else {
          const unsigned* p = Gu + (h >> 1);
          unsigned d0 = p[0], d1 = p[1], d2 = p[2], d3 = p[3], d4 = p[4];
          if (h & 1) {
            bb.d[0] = (d0 >> 16) | (d1 << 16); bb.d[1] = (d1 >> 16) | (d2 << 16);
            bb.d[2] = (d2 >> 16) | (d3 << 16); bb.d[3] = (d3 >> 16) | (d4 << 16);
          } else {
            bb.d[0] = d0; bb.d[1] = d1; bb.d[2] = d2; bb.d[3] = d3;
          }
        }
        B[tb][u] = bb.v;
      }
#pragma unroll
    for (int i = 0; i < OTB; i++)
#pragma unroll
      for (int tb = 0; tb < TB; tb++)
#pragma unroll
        for (int u = 0; u < 2; u++)
          acc[i][tb][u] =
              __builtin_amdgcn_mfma_f32_16x16x32_bf16(A[i], B[tb][u], acc[i][tb][u], 0, 0, 0);
  }

  if (CIN >= 32) {
    // residual via MFMA from c-innermost Xt
    for (int kcr = 0; kcr < KCR; kcr++) {
      bf16x8 A[OTB];
#pragma unroll
      for (int i = 0; i < OTB; i++)
        A[i] = *(const bf16x8*)(Ar + (((size_t)(otg * OTB + i) * KCR + kcr) * 64 + lane) * 8);
#pragma unroll
      for (int tb = 0; tb < TB; tb++)
#pragma unroll
        for (int u = 0; u < 2; u++) {
          int t = S * (to_base + tb * 16 + nn);
          bf16x8 B = *(const bf16x8*)(Xt + (((size_t)n * 18 + v0 + u) * TIN + t) * CIN +
                                      kcr * 32 + q * 8);
#pragma unroll
          for (int i = 0; i < OTB; i++)
            acc[i][tb][u] =
                __builtin_amdgcn_mfma_f32_16x16x32_bf16(A[i], B, acc[i][tb][u], 0, 0, 0);
        }
    }
  } else {
    // block-1 residual: CIN=2 fp32 VALU from XB
#pragma unroll
    for (int ci = 0; ci < 2; ci++) {
#pragma unroll
      for (int tb = 0; tb < TB; tb++)
#pragma unroll
        for (int u = 0; u < 2; u++) {
          float xv =
              XB[(((size_t)n * 2 + ci) * 18 + v0 + u) * TIN + S * (to_base + tb * 16 + nn)];
#pragma unroll
          for (int i = 0; i < OTB; i++) {
            const float4 w4 = *(const float4*)&rwT1[ci * CO + (otg * OTB + i) * 16 + q * 4];
            acc[i][tb][u][0] = fmaf(w4.x, xv, acc[i][tb][u][0]);
            acc[i][tb][u][1] = fmaf(w4.y, xv, acc[i][tb][u][1]);
            acc[i][tb][u][2] = fmaf(w4.z, xv, acc[i][tb][u][2]);
            acc[i][tb][u][3] = fmaf(w4.w, xv, acc[i][tb][u][3]);
          }
        }
    }
  }

#pragma unroll
  for (int i = 0; i < OTB; i++) {
    int ob = (otg * OTB + i) * 16 + q * 4;
    const float4 bt = *(const float4*)&beta[ob];
#pragma unroll
    for (int tb = 0; tb < TB; tb++)
#pragma unroll
      for (int u = 0; u < 2; u++) {
        int v = v0 + u, to = to_base + tb * 16 + nn;
#pragma unroll
        for (int r = 0; r < 4; r++) {
          float val = acc[i][tb][u][r] + ((const float*)&bt)[r];
          Out[(((size_t)n * CO + ob + r) * 18 + v) * TOUT + to] = val > 0.0f ? val : 0.0f;
        }
      }
  }
}

// ------------------ EMA smooth + bf16 transposed emission ------------------
// grid (NC, 18, CO/64); block 64. X (n,CO,18,T) fp32 in-place; Xt (n,18,T,CO) bf16.
__global__ __launch_bounds__(64) void k_smooth2(
    float* __restrict__ X, unsigned short* __restrict__ Xt, int CO, int T) {
  __shared__ float tile[64 * 33];
  int n = blockIdx.x, v = blockIdx.y, c0 = blockIdx.z * 64;
  int tid = threadIdx.x;
  float s = 0.0f;
  for (int tc = 0; tc < T; tc += 32) {
    for (int e = tid; e < 64 * 32; e += 64) {
      int cc = e >> 5, tt = e & 31;
      tile[cc * 33 + tt] = X[((size_t)(n * CO + c0 + cc) * 18 + v) * T + tc + tt];
    }
    __syncthreads();
    float* row = &tile[tid * 33];
    int start = 0;
    if (tc == 0) { s = row[0]; start = 1; }
    for (int tt = start; tt < 32; tt++) {
      s = fmaf(0.85f, s, 0.15f * row[tt]);
      row[tt] = s;
    }
    __syncthreads();
    for (int e = tid; e < 64 * 32; e += 64) {
      int cc = e >> 5, tt = e & 31;
      X[((size_t)(n * CO + c0 + cc) * 18 + v) * T + tc + tt] = tile[cc * 33 + tt];
    }
    for (int it = 0; it < 32; it++)
      Xt[((size_t)(n * 18 + v) * T + tc + it) * CO + c0 + tid] = f2bf(tile[tid * 33 + it]);
    __syncthreads();
  }
}

// plain in-place EMA (final block; no Xt needed). rows contiguous length T.
__global__ __launch_bounds__(64) void k_smooth(float* __restrict__ X, int T) {
  __shared__ float tile[64 * 33];
  size_t r0 = (size_t)blockIdx.x * 64;
  float s = 0.0f;
  for (int tc = 0; tc < T; tc += 32) {
    for (int e = threadIdx.x; e < 64 * 32; e += 64) {
      int r = e >> 5, tt = e & 31;
      tile[r * 33 + tt] = X[(r0 + r) * T + tc + tt];
    }
    __syncthreads();
    float* row = &tile[threadIdx.x * 33];
    int start = 0;
    if (tc == 0) { s = row[0]; start = 1; }
    for (int tt = start; tt < 32; tt++) {
      s = fmaf(0.85f, s, 0.15f * row[tt]);
      row[tt] = s;
    }
    __syncthreads();
    for (int e = threadIdx.x; e < 64 * 32; e += 64) {
      int r = e >> 5, tt = e & 31;
      X[(r0 + r) * T + tc + tt] = tile[r * 33 + tt];
    }
    __syncthreads();
  }
}

// mean over (v,t)=1152 then 10-way FC.  H:(nc,256,18,64)
__global__ __launch_bounds__(256, 4) void k_poolfc(
    const float* __restrict__ H, const float* __restrict__ fcw,
    const float* __restrict__ fcb, float* __restrict__ out) {
  int n = blockIdx.x;
  __shared__ float pool[256];
  const float* row = H + (size_t)(n * 256 + threadIdx.x) * 1152;
  float s = 0.0f;
  for (int i = 0; i < 1152; i += 4) {
    float4 x4 = *(const float4*)&row[i];
    s += x4.x + x4.y + x4.z + x4.w;
  }
  pool[threadIdx.x] = s * (1.0f / 1152.0f);
  __syncthreads();
  if (threadIdx.x < 10) {
    float a = fcb[threadIdx.x];
    for (int c = 0; c < 256; c++) a = fmaf(fcw[threadIdx.x * 256 + c], pool[c], a);
    out[n * 10 + threadIdx.x] = a;
  }
}

extern "C" void kernel_launch(void* const* d_in, const int* in_sizes, int n_in,
                              void* d_out, int out_size, void* d_ws, size_t ws_size,
                              hipStream_t stream) {
  const float* x    = (const float*)d_in[0];
  const float* Amat = (const float*)d_in[1];
  const float* dbng = (const float*)d_in[2];
  const float* dbnb = (const float*)d_in[3];
  const float* gw1 = (const float*)d_in[4];   const float* gb1 = (const float*)d_in[5];
  const float* bn1g1 = (const float*)d_in[6]; const float* bn1b1 = (const float*)d_in[7];
  const float* tw1 = (const float*)d_in[8];   const float* tb1 = (const float*)d_in[9];
  const float* bn2g1 = (const float*)d_in[10]; const float* bn2b1 = (const float*)d_in[11];
  const float* rw1 = (const float*)d_in[12];  const float* rb1 = (const float*)d_in[13];
  const float* gw2 = (const float*)d_in[14];  const float* gb2 = (const float*)d_in[15];
  const float* bn1g2 = (const float*)d_in[16]; const float* bn1b2 = (const float*)d_in[17];
  const float* tw2 = (const float*)d_in[18];  const float* tb2 = (const float*)d_in[19];
  const float* bn2g2 = (const float*)d_in[20]; const float* bn2b2 = (const float*)d_in[21];
  const float* rw2 = (const float*)d_in[22];  const float* rb2 = (const float*)d_in[23];
  const float* gw3 = (const float*)d_in[24];  const float* gb3 = (const float*)d_in[25];
  const float* bn1g3 = (const float*)d_in[26]; const float* bn1b3 = (const float*)d_in[27];
  const float* tw3 = (const float*)d_in[28];  const float* tb3 = (const float*)d_in[29];
  const float* bn2g3 = (const float*)d_in[30]; const float* bn2b3 = (const float*)d_in[31];
  const float* rw3 = (const float*)d_in[32];  const float* rb3 = (const float*)d_in[33];
  const float* fcw = (const float*)d_in[34];  const float* fcb = (const float*)d_in[35];
  (void)in_sizes; (void)n_in; (void)out_size;

  // ---- weights region at ws base ----
  float* f = (float*)d_ws;
  float* rwT1  = f;             // 128
  float* beta1 = rwT1 + 128;    // 64
  float* beta2 = beta1 + 64;    // 128
  float* beta3 = beta2 + 128;   // 256
  // pad to 1024 floats
  unsigned short* H = (unsigned short*)(f + 1024);
  unsigned short* Ac1 = H;                 // 65536
  unsigned short* Ac2 = Ac1 + 65536;       // 262144
  unsigned short* Ac3 = Ac2 + 262144;      // 1048576
  unsigned short* Ar2 = Ac3 + 1048576;     // 8192
  unsigned short* Ar3 = Ar2 + 8192;        // 32768
  unsigned short* Ag2 = Ar3 + 32768;       // 8192
  unsigned short* Ag3 = Ag2 + 8192;        // 32768
  const size_t WOFFB = 4096 + 1458176ULL * 2;  // 2,920,448 bytes

  // ---- pick largest chunk NC that fits ws_size ----
  // per-n: U 2359296 + B1/B2 2*1179648 + XB 36864 (fp32 bytes)
  //        + G 663552*2 + Xt 294912*2 (bf16 bytes) = 6,672,384 B
  int NC = 32;
  while (NC > 1 && WOFFB + (size_t)NC * 6672384ULL + 64 > ws_size) NC >>= 1;
  float* U  = f + (WOFFB / 4);
  float* B1 = U + (size_t)NC * 589824;
  float* B2 = B1 + (size_t)NC * 294912;
  float* XB = B2 + (size_t)NC * 294912;
  unsigned short* G  = (unsigned short*)(XB + (size_t)NC * 9216);
  unsigned short* Xt = G + (size_t)NC * 663552 + 16;

  // ---- weight prep (idempotent) ----
  k_transpose<<<1, 256, 0, stream>>>(rw1, rwT1, 64, 2);
  k_beta<<<1, 256, 0, stream>>>(bn2g1, bn2b1, tb1, rb1, beta1, 64);
  k_beta<<<1, 256, 0, stream>>>(bn2g2, bn2b2, tb2, rb2, beta2, 128);
  k_beta<<<1, 256, 0, stream>>>(bn2g3, bn2b3, tb3, rb3, beta3, 256);
  k_pack_conv<<<256, 256, 0, stream>>>(tw1, bn2g1, Ac1, 64);
  k_pack_conv<<<1024, 256, 0, stream>>>(tw2, bn2g2, Ac2, 128);
  k_pack_conv<<<4096, 256, 0, stream>>>(tw3, bn2g3, Ac3, 256);
  k_pack_k32<<<32, 256, 0, stream>>>(rw2, Ar2, 64, 128);
  k_pack_k32<<<128, 256, 0, stream>>>(rw3, Ar3, 128, 256);
  k_pack_k32<<<32, 256, 0, stream>>>(gw2, Ag2, 64, 128);
  k_pack_k32<<<128, 256, 0, stream>>>(gw3, Ag3, 128, 256);

  // ---- network per N-chunk ----
  for (int n0 = 0; n0 < 128; n0 += NC) {
    // block 1
    k_front1<<<dim3(NC, 4), 256, 0, stream>>>(
        x + (size_t)n0 * 9216, dbng, dbnb, gw1, U, XB);
    k_amixg<256><<<NC * 64, 256, 0, stream>>>(U, G, Amat, gb1, bn1g1, bn1b1, 64);
    k_conv<2, 64, 1, 256, 256, 4, 2><<<dim3(NC, 8, 9), 64, 0, stream>>>(
        G, nullptr, XB, Ac1, nullptr, rwT1, beta1, B1);
    k_smooth2<<<dim3(NC, 18, 1), 64, 0, stream>>>(B1, Xt, 64, 256);
    // block 2
    k_ugemm_m<64, 128><<<dim3(NC, 144, 4), 64, 0, stream>>>(Xt, Ag2, U, 4608);
    k_amixg<256><<<NC * 128, 256, 0, stream>>>(U, G, Amat, gb2, bn1g2, bn1b2, 128);
    k_conv<64, 128, 2, 256, 128, 4, 2><<<dim3(NC, 4, 18), 64, 0, stream>>>(
        G, Xt, nullptr, Ac2, Ar2, nullptr, beta2, B2);
    k_smooth2<<<dim3(NC, 18, 2), 64, 0, stream>>>(B2, Xt, 128, 128);
    // block 3 (output reuses B1)
    k_ugemm_m<128, 256><<<dim3(NC, 72, 8), 64, 0, stream>>>(Xt, Ag3, U, 2304);
    k_amixg<128><<<NC * 128, 256, 0, stream>>>(U, G, Amat, gb3, bn1g3, bn1b3, 256);
    k_conv<128, 256, 2, 128, 64, 4, 2><<<dim3(NC, 2, 36), 64, 0, stream>>>(
        G, Xt, nullptr, Ac3, Ar3, nullptr, beta3, B1);
    k_smooth<<<NC * 72, 64, 0, stream>>>(B1, 64);
    // head
    k_poolfc<<<NC, 256, 0, stream>>>(B1, fcw, fcb, (float*)d_out + (size_t)n0 * 10);
  }
}